// Round 4
// baseline (92.239 us; speedup 1.0000x reference)
//
#include <hip/hip_runtime.h>
#include <stdint.h>

#define NR 16384
#define KI 256
#define MO 128
#define ALPHA 0.01f
#define CH 16             // rows per chunk
#define NCH (NR / CH)     // 1024 chunks
#define RB 8              // i-keys per thread in k_rank
#define JT 128            // j-keys staged in LDS per block
#define NJ (NR / JT)      // 128 j-chunks

typedef unsigned long long u64;

// sortable key: monotone float order, index tie-break (rank is a bijection)
static __device__ __forceinline__ u64 sort_key(float f, int j) {
    unsigned u = __float_as_uint(f);
    u ^= ((unsigned)((int)u >> 31)) | 0x80000000u;
    return (((u64)u) << 14) | (unsigned)(j & 0x3FFF);
}

// ---------------- K1: h = x@W^T (64x128 tile, 512 thr, reg-prefetch) + fused s1,s2,keys ----------------
__global__ __launch_bounds__(512) void k_gemm_fused(const float* __restrict__ x,
                                                    const float* __restrict__ w,
                                                    const float* __restrict__ a1,
                                                    const float* __restrict__ a2,
                                                    float* __restrict__ h,
                                                    float* __restrict__ s1,
                                                    float* __restrict__ s2,
                                                    u64* __restrict__ keys) {
    __shared__ float As[16][65];    // [k][row 0..63]
    __shared__ float Bs0[16][68];   // [k][col 0..63]   (68*4=272B, 16B-aligned stride)
    __shared__ float Bs1[16][68];   // [k][col 64..127]
    const int t = threadIdx.x;
    const int rowBase = blockIdx.x * 64;
    const int tx = t & 15;          // cols tx*4 (low) and 64+tx*4 (high)
    const int ty = t >> 4;          // rows ty*2, ty*2+1
    const int ar = t >> 2, ak = (t & 3) << 2;   // A staging (t<256)
    const int br = t >> 2, bk = (t & 3) << 2;   // B staging (all 512)
    float acc[2][8] = {};

    float4 av = {}, bv = {};
    if (t < 256) av = *(const float4*)&x[(rowBase + ar) * KI + ak];
    bv = *(const float4*)&w[br * KI + bk];

    for (int k0 = 0; k0 < KI; k0 += 16) {
        __syncthreads();
        if (t < 256) {
            As[ak + 0][ar] = av.x; As[ak + 1][ar] = av.y;
            As[ak + 2][ar] = av.z; As[ak + 3][ar] = av.w;
        }
        if (br < 64) {
            Bs0[bk + 0][br] = bv.x; Bs0[bk + 1][br] = bv.y;
            Bs0[bk + 2][br] = bv.z; Bs0[bk + 3][br] = bv.w;
        } else {
            Bs1[bk + 0][br - 64] = bv.x; Bs1[bk + 1][br - 64] = bv.y;
            Bs1[bk + 2][br - 64] = bv.z; Bs1[bk + 3][br - 64] = bv.w;
        }
        __syncthreads();
        if (k0 + 16 < KI) {   // prefetch next K-step while computing this one
            if (t < 256) av = *(const float4*)&x[(rowBase + ar) * KI + k0 + 16 + ak];
            bv = *(const float4*)&w[br * KI + k0 + 16 + bk];
        }
#pragma unroll
        for (int k = 0; k < 16; ++k) {
            float a0 = As[k][ty * 2];
            float a1r = As[k][ty * 2 + 1];
            float4 b0 = *(const float4*)&Bs0[k][tx << 2];
            float4 b1 = *(const float4*)&Bs1[k][tx << 2];
            float b[8] = {b0.x, b0.y, b0.z, b0.w, b1.x, b1.y, b1.z, b1.w};
#pragma unroll
            for (int j = 0; j < 8; ++j) {
                acc[0][j] = fmaf(a0, b[j], acc[0][j]);
                acc[1][j] = fmaf(a1r, b[j], acc[1][j]);
            }
        }
    }
    // write h: rows ty*2+r, cols tx*4 and 64+tx*4
#pragma unroll
    for (int r = 0; r < 2; ++r) {
        float4 st0 = {acc[r][0], acc[r][1], acc[r][2], acc[r][3]};
        float4 st1 = {acc[r][4], acc[r][5], acc[r][6], acc[r][7]};
        float* hp = &h[(size_t)(rowBase + ty * 2 + r) * MO];
        *(float4*)(hp + (tx << 2)) = st0;
        *(float4*)(hp + 64 + (tx << 2)) = st1;
    }
    // fused s1,s2,keys
    float4 a1lo = *(const float4*)&a1[tx << 2];
    float4 a1hi = *(const float4*)&a1[64 + (tx << 2)];
    float4 a2lo = *(const float4*)&a2[tx << 2];
    float4 a2hi = *(const float4*)&a2[64 + (tx << 2)];
    float a1v[8] = {a1lo.x, a1lo.y, a1lo.z, a1lo.w, a1hi.x, a1hi.y, a1hi.z, a1hi.w};
    float a2v[8] = {a2lo.x, a2lo.y, a2lo.z, a2lo.w, a2hi.x, a2hi.y, a2hi.z, a2hi.w};
#pragma unroll
    for (int r = 0; r < 2; ++r) {
        float p1 = 0.f, p2 = 0.f;
#pragma unroll
        for (int c = 0; c < 8; ++c) {
            p1 = fmaf(acc[r][c], a1v[c], p1);
            p2 = fmaf(acc[r][c], a2v[c], p2);
        }
#pragma unroll
        for (int off = 8; off; off >>= 1) {   // reduce over tx (lane bits 0..3)
            p1 += __shfl_xor(p1, off, 64);
            p2 += __shfl_xor(p2, off, 64);
        }
        if (tx == 0) {
            int row = rowBase + ty * 2 + r;
            s1[row] = p1;
            s2[row] = p2;
            keys[row] = sort_key(p1, row);
        }
    }
}

// ---------------- K2: rank partials — LDS-broadcast j-keys, 8 i-keys/thread in VGPRs ----------------
__global__ __launch_bounds__(256) void k_rank(const u64* __restrict__ keys,
                                              int* __restrict__ rankPart) {
    __shared__ u64 sk[JT];
    const int t = threadIdx.x;
    const int ibase = blockIdx.x * (256 * RB);
    const int jbase = blockIdx.y * JT;
    if (t < JT) sk[t] = keys[jbase + t];
    u64 ki[RB];
#pragma unroll
    for (int k = 0; k < RB; ++k) ki[k] = keys[ibase + k * 256 + t];
    int cnt[RB] = {};
    __syncthreads();
#pragma unroll 4
    for (int jj = 0; jj < JT; ++jj) {
        u64 kj = sk[jj];                 // uniform addr -> LDS broadcast
#pragma unroll
        for (int k = 0; k < RB; ++k)
            cnt[k] += (kj < ki[k]) ? 1 : 0;
    }
#pragma unroll
    for (int k = 0; k < RB; ++k)
        rankPart[blockIdx.y * NR + ibase + k * 256 + t] = cnt[k];
}

// ---------------- K3: sum partials, scatter into sorted order ----------------
__global__ __launch_bounds__(256) void k_scatter(const float* __restrict__ s1,
                                                 const int* __restrict__ rankPart,
                                                 float* __restrict__ s1s,
                                                 int* __restrict__ perm) {
    int i = blockIdx.x * 256 + threadIdx.x;
    int r = 0;
    for (int p = 0; p < NJ; ++p) r += rankPart[p * NR + i];
    s1s[r] = s1[i];
    perm[r] = i;
}

// ---------------- K4: per-chunk partial sums of sorted h, s1*h  (psum layout [c][q]) ----------------
__global__ __launch_bounds__(128) void k_psum(const float* __restrict__ h,
                                              const int* __restrict__ perm,
                                              const float* __restrict__ s1s,
                                              float* __restrict__ psumH,
                                              float* __restrict__ psumSH) {
    __shared__ int pi[CH];
    __shared__ float ss[CH];
    const int c = threadIdx.x, q = blockIdx.x;
    if (c < CH) { pi[c] = perm[q * CH + c]; ss[c] = s1s[q * CH + c]; }
    __syncthreads();
    float sh = 0.f, sv = 0.f;
#pragma unroll
    for (int m = 0; m < CH; ++m) {
        float v = h[(size_t)pi[m] * MO + c];
        sh += v;
        sv = fmaf(ss[m], v, sv);
    }
    psumH[c * NCH + q] = sh;
    psumSH[c * NCH + q] = sv;
}

// ---------------- K5: exclusive suffix scan over 1024 chunk sums (block per column, shfl-based) ----------------
__global__ __launch_bounds__(1024) void k_scan(const float* __restrict__ psumH,
                                               const float* __restrict__ psumSH,
                                               float* __restrict__ cSufH,
                                               float* __restrict__ cSufS,
                                               float* __restrict__ SH,
                                               float* __restrict__ SSH) {
    const int c = blockIdx.x, q = threadIdx.x;
    const int lane = q & 63, wv = q >> 6;      // 16 waves
    float vh = psumH[c * NCH + q], vs = psumSH[c * NCH + q];
    float ih = vh, is = vs;
#pragma unroll
    for (int off = 1; off < 64; off <<= 1) {   // wave-level inclusive suffix scan
        float th = __shfl_down(ih, off, 64);
        float ts = __shfl_down(is, off, 64);
        if (lane + off < 64) { ih += th; is += ts; }
    }
    __shared__ float wtH[16], wtS[16], corrH[16], corrS[16];
    if (lane == 0) { wtH[wv] = ih; wtS[wv] = is; }   // wave totals
    __syncthreads();
    if (q < 16) {
        float chh = 0.f, cs = 0.f;
        for (int w2 = q + 1; w2 < 16; ++w2) { chh += wtH[w2]; cs += wtS[w2]; }
        corrH[q] = chh; corrS[q] = cs;
    }
    __syncthreads();
    float sufH = ih + corrH[wv] - vh;   // exclusive suffix (chunks > q)
    float sufS = is + corrS[wv] - vs;
    cSufH[q * MO + c] = sufH;
    cSufS[q * MO + c] = sufS;
    if (q == 0) { SH[(size_t)NR * MO + c] = 0.f; SSH[(size_t)NR * MO + c] = 0.f; }
}

// ---------------- K6: full suffix arrays SH[k], SSH[k] ----------------
__global__ __launch_bounds__(128) void k_suffix(const float* __restrict__ h,
                                                const int* __restrict__ perm,
                                                const float* __restrict__ s1s,
                                                const float* __restrict__ cSufH,
                                                const float* __restrict__ cSufS,
                                                float* __restrict__ SH,
                                                float* __restrict__ SSH) {
    __shared__ int pi[CH];
    __shared__ float ss[CH];
    const int c = threadIdx.x, q = blockIdx.x;
    if (c < CH) { pi[c] = perm[q * CH + c]; ss[c] = s1s[q * CH + c]; }
    __syncthreads();
    float runH = cSufH[q * MO + c], runS = cSufS[q * MO + c];
#pragma unroll
    for (int m = CH - 1; m >= 0; --m) {
        int gm = q * CH + m;
        float v = h[(size_t)pi[m] * MO + c];
        runH += v;
        runS = fmaf(ss[m], v, runS);
        SH[(size_t)gm * MO + c] = runH;
        SSH[(size_t)gm * MO + c] = runS;
    }
}

// ---------------- K7: out[i][c], binary search fused (2 rows per block) ----------------
__global__ __launch_bounds__(256) void k_final(const float* __restrict__ SH,
                                               const float* __restrict__ SSH,
                                               const float* __restrict__ s1s,
                                               const float* __restrict__ s2,
                                               float* __restrict__ out) {
    const int t = threadIdx.x;
    const int i = blockIdx.x * 2 + (t >> 7);
    const int c = t & 127;
    float s2v = s2[i];
    float tv = -s2v;
    int lo = 0, hi = NR;
    while (lo < hi) {                 // uniform per half-block; TLP hides the chain
        int mid = (lo + hi) >> 1;
        if (s1s[mid] < tv) lo = mid + 1; else hi = mid;
    }
    float th = SH[c], tsh = SSH[c];   // suffix from 0 = totals (L2-hot)
    float sh = SH[(size_t)lo * MO + c], sshv = SSH[(size_t)lo * MO + c];
    out[(size_t)i * MO + c] = ALPHA * fmaf(s2v, th, tsh) + (1.f - ALPHA) * fmaf(s2v, sh, sshv);
}

extern "C" void kernel_launch(void* const* d_in, const int* in_sizes, int n_in,
                              void* d_out, int out_size, void* d_ws, size_t ws_size,
                              hipStream_t stream) {
    const float* x  = (const float*)d_in[0];
    const float* w  = (const float*)d_in[1];
    const float* a1 = (const float*)d_in[2];
    const float* a2 = (const float*)d_in[3];
    float* out = (float*)d_out;

    float* ws     = (float*)d_ws;
    float* h      = ws;                               // NR*MO
    float* SH     = h + (size_t)NR * MO;              // (NR+1)*MO
    float* SSH    = SH + (size_t)(NR + 1) * MO;       // (NR+1)*MO
    float* s1     = SSH + (size_t)(NR + 1) * MO;      // NR
    float* s2     = s1 + NR;                          // NR
    float* s1s    = s2 + NR;                          // NR
    u64*   keys   = (u64*)(s1s + NR);                 // NR u64
    int*   perm   = (int*)(keys + NR);                // NR
    float* psumH  = (float*)(perm + NR);              // MO*NCH  ([c][q])
    float* psumSH = psumH + MO * NCH;                 // MO*NCH
    float* cSufH  = psumSH + MO * NCH;                // NCH*MO  ([q][c])
    float* cSufS  = cSufH + NCH * MO;                 // NCH*MO
    // rankPart (NJ*NR ints = 8 MB) aliases SH ((NR+1)*MO*4 = 8.39 MB): dead before SH written
    int*   rankPart = (int*)SH;

    k_gemm_fused<<<NR / 64, 512, 0, stream>>>(x, w, a1, a2, h, s1, s2, keys);
    k_rank<<<dim3(NR / (256 * RB), NJ), 256, 0, stream>>>(keys, rankPart);
    k_scatter<<<NR / 256, 256, 0, stream>>>(s1, rankPart, s1s, perm);
    k_psum<<<NCH, 128, 0, stream>>>(h, perm, s1s, psumH, psumSH);
    k_scan<<<MO, NCH, 0, stream>>>(psumH, psumSH, cSufH, cSufS, SH, SSH);
    k_suffix<<<NCH, 128, 0, stream>>>(h, perm, s1s, cSufH, cSufS, SH, SSH);
    k_final<<<NR / 2, 256, 0, stream>>>(SH, SSH, s1s, s2, out);
}